// Round 1
// 3949.135 us; speedup vs baseline: 1.6277x; 1.6277x over previous
//
#include <hip/hip_runtime.h>

// Problem constants (B=8, C=32, H=192, W=320)
#define IMH 192
#define IMW 320
#define HW_ (IMH * IMW)      // 61440
#define BB 8
#define FC 32
#define GR 8                 // gather radius: covers |disp| < 8 (~4 sigma)

typedef unsigned short ushortT;
typedef __attribute__((ext_vector_type(8))) short short8;   // 8 bf16 = 4 VGPRs
typedef __attribute__((ext_vector_type(4))) float f32x4;

union FragU { uint4 u; short8 s8; };

__device__ __forceinline__ ushortT f2bf(float x) {
    union { float f; unsigned u; } v; v.f = x;
    unsigned r = v.u + 0x7FFF + ((v.u >> 16) & 1);   // RNE
    return (ushortT)(r >> 16);
}
__device__ __forceinline__ float lk(float v) { return (v >= 0.f) ? v : 0.1f * v; }

// ---------------------------------------------------------------------------
// 1. bilinear 2x upsample (half-pixel centers, edge clamp) * 2.0  [full batch]
// ---------------------------------------------------------------------------
__global__ __launch_bounds__(256) void upsample_k(const float* __restrict__ in,
                                                  float* __restrict__ out) {
    int gid = blockIdx.x * 256 + threadIdx.x;
    const int total = BB * 4 * IMH * IMW;
    if (gid >= total) return;
    int ox = gid % IMW;
    int t  = gid / IMW;
    int oy = t % IMH;
    int bc = t / IMH;
    const int Hin = IMH / 2, Win = IMW / 2;
    float sy = oy * 0.5f - 0.25f;
    float sx = ox * 0.5f - 0.25f;
    float fy = floorf(sy), fx = floorf(sx);
    float ty_ = sy - fy, tx_ = sx - fx;
    int y0 = (int)fy, x0 = (int)fx;
    int y1 = y0 + 1, x1 = x0 + 1;
    y0 = max(0, min(Hin - 1, y0)); y1 = max(0, min(Hin - 1, y1));
    x0 = max(0, min(Win - 1, x0)); x1 = max(0, min(Win - 1, x1));
    const float* p = in + (long)bc * Hin * Win;
    float v00 = p[y0 * Win + x0], v01 = p[y0 * Win + x1];
    float v10 = p[y1 * Win + x0], v11 = p[y1 * Win + x1];
    float v = (1.f - ty_) * ((1.f - tx_) * v00 + tx_ * v01) +
              ty_ * ((1.f - tx_) * v10 + tx_ * v11);
    out[gid] = 2.f * v;
}

// ---------------------------------------------------------------------------
// 2. zero-init (16B granules)
// ---------------------------------------------------------------------------
__global__ __launch_bounds__(256) void zero4_k(uint4* __restrict__ p, long n) {
    long gid = (long)blockIdx.x * 256 + threadIdx.x;
    long stride = (long)gridDim.x * 256;
    uint4 z = make_uint4(0, 0, 0, 0);
    for (long i = gid; i < n; i += stride) p[i] = z;
}

// ---------------------------------------------------------------------------
// 3a. NCHW fp32 -> NHWC fp32 transpose (per group, into bufA/bufB alias)
// ---------------------------------------------------------------------------
__global__ __launch_bounds__(256) void tr_nhwc_k(const float* __restrict__ in,
                                                 float* __restrict__ out, int nb) {
    int gid = blockIdx.x * 256 + threadIdx.x;
    if (gid >= nb * HW_) return;
    int b = gid / HW_;
    int p = gid - b * HW_;
    const float* src = in + (long)b * FC * HW_ + p;
    float buf[FC];
#pragma unroll
    for (int c = 0; c < FC; ++c) buf[c] = src[(long)c * HW_];
    float4* dst = (float4*)(out + ((long)b * HW_ + p) * FC);
#pragma unroll
    for (int c4 = 0; c4 < FC / 4; ++c4)
        dst[c4] = make_float4(buf[c4 * 4 + 0], buf[c4 * 4 + 1],
                              buf[c4 * 4 + 2], buf[c4 * 4 + 3]);
}

// ---------------------------------------------------------------------------
// 3b. outlier splat: corner-events the gather window can't see (|d| > GR).
//     EXACT complement of gather coverage, decided per corner. Rare (~4sigma),
//     so the atomic path here is negligible.
// ---------------------------------------------------------------------------
__global__ __launch_bounds__(256) void outlier_k(const float* __restrict__ feat,
                                                 const float* __restrict__ biflow,
                                                 int fbase,
                                                 float* __restrict__ acc, int nb) {
    int gid = blockIdx.x * 256 + threadIdx.x;
    if (gid >= nb * HW_) return;
    int b = gid / HW_;
    int p = gid - b * HW_;
    int y = p / IMW, x = p - y * IMW;
    const float* fl = biflow + ((long)b * 4 + fbase) * HW_;
    float fx = x + fl[p];
    float fy = y + fl[HW_ + p];
    float x0f = floorf(fx), y0f = floorf(fy);
    int ix0 = (int)x0f, iy0 = (int)y0f;
    // fully covered by gather window? (both corners within +-GR on both axes)
    if (ix0 >= x - GR && ix0 + 1 <= x + GR && iy0 >= y - GR && iy0 + 1 <= y + GR)
        return;
    float wx1 = fx - x0f, wy1 = fy - y0f;
    float wx0 = 1.f - wx1, wy0 = 1.f - wy1;
    float f[FC];
#pragma unroll
    for (int c = 0; c < FC; ++c) f[c] = feat[((long)b * FC + c) * HW_ + p];
    float* accb = acc + (long)b * 33 * HW_;
    const int ixs[4] = {ix0, ix0 + 1, ix0, ix0 + 1};
    const int iys[4] = {iy0, iy0, iy0 + 1, iy0 + 1};
    const float ww[4] = {wx0 * wy0, wx1 * wy0, wx0 * wy1, wx1 * wy1};
#pragma unroll
    for (int k = 0; k < 4; ++k) {
        int ix = ixs[k], iy = iys[k];
        float w = ww[k];
        if (ix < 0 || ix >= IMW || iy < 0 || iy >= IMH || w == 0.f) continue;
        // covered by gather? then the gather pass adds it -> skip here
        int dx = ix - x, dy = iy - y;
        if (dx >= -GR && dx <= GR && dy >= -GR && dy <= GR) continue;
        int q = iy * IMW + ix;
#pragma unroll
        for (int c = 0; c < FC; ++c) atomicAdd(&accb[c * HW_ + q], f[c] * w);
        atomicAdd(&accb[32 * HW_ + q], w);
    }
}

// ---------------------------------------------------------------------------
// 3c. gather splat + normalize (fused). One thread per OUTPUT pixel.
//     Tile 64x4, window (64+2R)x(4+2R)=80x20 float2 of absolute targets in LDS.
//     Candidate p matches output (ox,oy) iff floor(target) in {o-1,o} per axis.
//     Features read from NHWC fp32 (8x float4 per match). No atomics.
// ---------------------------------------------------------------------------
__global__ __launch_bounds__(256) void gather_k(const float* __restrict__ tfeat,
                                                const float* __restrict__ biflow,
                                                int fbase,
                                                float* __restrict__ acc) {
    const int b = blockIdx.z;
    const int xBase = blockIdx.x * 64;
    const int yBase = blockIdx.y * 4;
    __shared__ float2 sF[20][80];   // 12.8 KB

    const float* fl = biflow + ((long)b * 4 + fbase) * HW_;
    for (int u = threadIdx.x; u < 20 * 80; u += 256) {
        int wy = u / 80, wx = u - wy * 80;
        int gy = yBase - GR + wy, gx = xBase - GR + wx;
        float2 t = make_float2(-1e9f, -1e9f);   // sentinel: never matches
        if ((unsigned)gy < IMH && (unsigned)gx < IMW) {
            int p = gy * IMW + gx;
            t.x = gx + fl[p];        // MUST match outlier_k's "x + fl[p]" exactly
            t.y = gy + fl[HW_ + p];
        }
        sF[wy][wx] = t;
    }

    const int lx = threadIdx.x & 63, ly = threadIdx.x >> 6;
    const int ox = xBase + lx, oy = yBase + ly;
    const int q = oy * IMW + ox;
    float* accb = acc + (long)b * 33 * HW_;

    // init from outlier contributions (mostly zero, cheap coalesced reads)
    float s[FC];
#pragma unroll
    for (int c = 0; c < FC; ++c) s[c] = accb[(long)c * HW_ + q];
    float nsum = accb[(long)32 * HW_ + q];

    __syncthreads();

    const float* tb = tfeat + (long)b * HW_ * FC;
    const int pBase = (yBase - GR + ly) * IMW + (xBase - GR + lx);

    for (int dy = 0; dy < 2 * GR + 1; ++dy) {
#pragma unroll 1
        for (int dx = 0; dx < 2 * GR + 1; ++dx) {
            float2 t = sF[ly + dy][lx + dx];
            float x0f = floorf(t.x), y0f = floorf(t.y);
            int dxm = ox - (int)x0f;
            int dym = oy - (int)y0f;
            if (((unsigned)dxm <= 1u) && ((unsigned)dym <= 1u)) {
                float wx1 = t.x - x0f, wy1 = t.y - y0f;
                float w = (dxm ? wx1 : 1.f - wx1) * (dym ? wy1 : 1.f - wy1);
                if (w != 0.f) {
                    nsum += w;
                    int pp = pBase + dy * IMW + dx;
                    const float4* fp = (const float4*)(tb + (long)pp * FC);
#pragma unroll
                    for (int c4 = 0; c4 < FC / 4; ++c4) {
                        float4 v = fp[c4];
                        s[c4 * 4 + 0] = fmaf(w, v.x, s[c4 * 4 + 0]);
                        s[c4 * 4 + 1] = fmaf(w, v.y, s[c4 * 4 + 1]);
                        s[c4 * 4 + 2] = fmaf(w, v.z, s[c4 * 4 + 2]);
                        s[c4 * 4 + 3] = fmaf(w, v.w, s[c4 * 4 + 3]);
                    }
                }
            }
        }
    }

    float inv = (nsum == 0.f) ? 1.f : (1.f / nsum);
#pragma unroll
    for (int c = 0; c < FC; ++c) accb[(long)c * HW_ + q] = s[c] * inv;
}

// ---------------------------------------------------------------------------
// 5. correlation volume (9x9, mean over 32 ch) + leaky -> concat ch64..144 bf16
// ---------------------------------------------------------------------------
__global__ __launch_bounds__(256) void corr_k(const float* __restrict__ w0,
                                              const float* __restrict__ w1,
                                              ushortT* __restrict__ concat, int nb) {
    int gid = blockIdx.x * 256 + threadIdx.x;
    if (gid >= nb * HW_) return;
    int b = gid / HW_;
    int p = gid - b * HW_;
    int y = p / IMW, x = p - y * IMW;
    const float* a0 = w0 + (long)b * 33 * HW_;
    const float* a1 = w1 + (long)b * 33 * HW_;
    float f[FC];
#pragma unroll
    for (int c = 0; c < FC; ++c) f[c] = a0[c * HW_ + p];
    ushortT* vb = concat + ((long)b * HW_ + p) * 160 + 64;
    for (int dy = 0; dy < 9; ++dy) {
        int yy = y + dy - 4;
        for (int dx = 0; dx < 9; ++dx) {
            int xx = x + dx - 4;
            float s = 0.f;
            if ((unsigned)yy < IMH && (unsigned)xx < IMW) {
                int q = yy * IMW + xx;
#pragma unroll
                for (int c = 0; c < FC; ++c) s = fmaf(f[c], a1[c * HW_ + q], s);
                s *= (1.f / 32.f);
            }
            vb[dy * 9 + dx] = f2bf(lk(s));
        }
    }
}

// ---------------------------------------------------------------------------
// 6. fill concat ch0..63: warped (fp32 NCHW, normalized) + temporal (pre-offset)
// ---------------------------------------------------------------------------
__global__ __launch_bounds__(256) void fill_k(const float* __restrict__ warp,
                                              const float* __restrict__ tf,
                                              ushortT* __restrict__ concat, int nb) {
    int gid = blockIdx.x * 256 + threadIdx.x;
    if (gid >= nb * HW_ * 8) return;
    int c8 = gid & 7;
    int t = gid >> 3;
    int p = t % HW_;
    int b = t / HW_;
    int ch = c8 * 8;
    const float* src = (ch < 32) ? warp + ((long)b * 33 + ch) * HW_ + p
                                 : tf + ((long)b * 32 + (ch - 32)) * HW_ + p;
    ushortT pk[8];
#pragma unroll
    for (int j = 0; j < 8; ++j) pk[j] = f2bf(src[(long)j * HW_]);
    *(uint4*)&concat[((long)b * HW_ + p) * 160 + ch] = *(uint4*)pk;
}

// ---------------------------------------------------------------------------
// 7. weight transform: W[oc][cin][3][3] fp32 -> Wb[tap][ocp][cinp] bf16 (pad 0)
// ---------------------------------------------------------------------------
__global__ __launch_bounds__(256) void wconv_k(const float* __restrict__ W,
                                               ushortT* __restrict__ dst,
                                               int OC, int OCp, int CIN, int CINp) {
    int gid = blockIdx.x * 256 + threadIdx.x;
    int total = 9 * OCp * CINp;
    if (gid >= total) return;
    int cin = gid % CINp;
    int t = gid / CINp;
    int oc = t % OCp;
    int tap = t / OCp;
    float v = 0.f;
    if (oc < OC && cin < CIN) v = W[((long)oc * CIN + cin) * 9 + tap];
    dst[gid] = f2bf(v);
}

// ---------------------------------------------------------------------------
// 8. MFMA implicit-GEMM conv3x3 (SAME). Block = 256 thr = 4 waves; tile = one
//    row x 64 px. Wave w owns 16-px N-tile, loops MT M-tiles (16 oc).
//    K = cin chunked by 32; 9 taps = 9 accumulated GEMMs.
// ---------------------------------------------------------------------------
template <int MT, int KC, bool LK, bool FIN>
__global__ __launch_bounds__(256) void mconv_k(
    const ushortT* __restrict__ act, int actStride, int cinReal,
    const ushortT* __restrict__ Wb,
    ushortT* __restrict__ outp, int outStride,
    const float* __restrict__ bfp, float* __restrict__ fout, int chBase) {

    const int CINp = KC * 32;
    const int OCp = MT * 16;
    const int tid = threadIdx.x;
    const int lane = tid & 63;
    const int wv = tid >> 6;
    const int l15 = lane & 15;
    const int quad = lane >> 4;
    const int x0 = blockIdx.x * 64;    // 5 tiles
    const int y = blockIdx.y;          // 192
    const int b = blockIdx.z;          // local batch

    __shared__ ushortT sAct[3 * 66 * 36];   // 14.26 KB

    f32x4 acc[MT];
#pragma unroll
    for (int i = 0; i < MT; ++i) acc[i] = (f32x4)0.f;

    const long pixBase = (long)b * HW_;

    for (int kc = 0; kc < KC; ++kc) {
        __syncthreads();
        // stage 3 rows x 66 px x 32 ch (4 units of 8ch per site)
        for (int u = tid; u < 3 * 66 * 4; u += 256) {
            int c8 = u & 3;
            int site = u >> 2;
            int ky = site / 66;
            int xi = site - ky * 66;
            int gy = y + ky - 1;
            int gx = x0 + xi - 1;
            int cBeg = kc * 32 + c8 * 8;
            ushortT* dp = &sAct[site * 36 + c8 * 8];
            if ((unsigned)gy < IMH && (unsigned)gx < IMW && cBeg < cinReal) {
                const ushortT* sp = act + ((pixBase + (long)gy * IMW + gx) * actStride + cBeg);
                if (cBeg + 8 <= cinReal) {
                    const uint2* sq = (const uint2*)sp;
                    ((uint2*)dp)[0] = sq[0];
                    ((uint2*)dp)[1] = sq[1];
                } else {
#pragma unroll
                    for (int j = 0; j < 8; ++j)
                        dp[j] = (cBeg + j < cinReal) ? sp[j] : (ushortT)0;
                }
            } else {
                uint2 z = make_uint2(0, 0);
                ((uint2*)dp)[0] = z;
                ((uint2*)dp)[1] = z;
            }
        }
        __syncthreads();

#pragma unroll
        for (int tap = 0; tap < 9; ++tap) {
            const int ky = tap / 3, kx = tap % 3;
            const int xi = wv * 16 + l15 + kx;
            const uint2* bp = (const uint2*)&sAct[(ky * 66 + xi) * 36 + quad * 8];
            FragU bf;
            uint2 b0 = bp[0], b1 = bp[1];
            bf.u = make_uint4(b0.x, b0.y, b1.x, b1.y);
            const ushortT* wp = Wb + (((long)tap * OCp + l15) * CINp + kc * 32 + quad * 8);
#pragma unroll
            for (int mt = 0; mt < MT; ++mt) {
                FragU af;
                af.u = *(const uint4*)(wp + (long)mt * 16 * CINp);
                acc[mt] = __builtin_amdgcn_mfma_f32_16x16x32_bf16(af.s8, bf.s8, acc[mt], 0, 0, 0);
            }
        }
    }

    const int px = x0 + wv * 16 + l15;
    if (FIN) {
        if (quad == 0) {
#pragma unroll
            for (int r = 0; r < 2; ++r) {
                float v = lk(acc[0][r]);
                long o = ((long)(b * 4 + chBase + r) * IMH + y) * IMW + px;
                fout[o] = bfp[o] + v;
            }
        }
    } else {
        long obase = (pixBase + (long)y * IMW + px) * outStride;
#pragma unroll
        for (int mt = 0; mt < MT; ++mt) {
            int oc = mt * 16 + quad * 4;
            ushortT pk[4];
#pragma unroll
            for (int r = 0; r < 4; ++r) {
                float v = acc[mt][r];
                if (LK) v = lk(v);
                pk[r] = f2bf(v);
            }
            *(uint2*)&outp[obase + oc] = *(uint2*)pk;
        }
    }
}

// ---------------------------------------------------------------------------
// launch — ws-size-adaptive batch grouping
// ---------------------------------------------------------------------------
extern "C" void kernel_launch(void* const* d_in, const int* in_sizes, int n_in,
                              void* d_out, int out_size, void* d_ws, size_t ws_size,
                              hipStream_t stream) {
    const float* f0  = (const float*)d_in[0];
    const float* f1  = (const float*)d_in[1];
    const float* bfp = (const float*)d_in[2];
    const float* ftf = (const float*)d_in[3];
    const float* btf = (const float*)d_in[4];
    const float* W1  = (const float*)d_in[5];
    const float* W2  = (const float*)d_in[6];
    const float* W3  = (const float*)d_in[7];
    const float* W4  = (const float*)d_in[8];
    const float* W5  = (const float*)d_in[9];
    const float* W6  = (const float*)d_in[10];
    const float* W7  = (const float*)d_in[11];
    float* out = (float*)d_out;

    char* base = (char*)d_ws;
    size_t off = 0;
    auto alloc = [&](size_t bytes) { char* p = base + off; off += (bytes + 255) & ~(size_t)255; return p; };

    float* biflow = (float*)alloc((size_t)BB * 4 * HW_ * 4);
    ushortT* WbL1 = (ushortT*)alloc((size_t)9 * 64 * 160 * 2);
    ushortT* WbL2 = (ushortT*)alloc((size_t)9 * 64 * 64 * 2);
    ushortT* WbL3 = (ushortT*)alloc((size_t)9 * 64 * 64 * 2);
    ushortT* WbL4 = (ushortT*)alloc((size_t)9 * 32 * 64 * 2);
    ushortT* WbL5 = (ushortT*)alloc((size_t)9 * 32 * 32 * 2);
    ushortT* WbL6 = (ushortT*)alloc((size_t)9 * 16 * 32 * 2);
    ushortT* WbL7 = (ushortT*)alloc((size_t)9 * 16 * 32 * 2);

    const size_t PERB = (size_t)840 * HW_;
    size_t remain = (ws_size > off + 4096) ? (ws_size - off - 4096) : 0;
    int NB = (int)(remain / (PERB + 2048));
    if (NB < 1) NB = 1;
    if (NB > BB) NB = BB;

    float*   acc0   = (float*)alloc((size_t)NB * 33 * HW_ * 4);
    float*   acc1   = (float*)alloc((size_t)NB * 33 * HW_ * 4);
    ushortT* concat = (ushortT*)alloc((size_t)NB * HW_ * 160 * 2);
    ushortT* bufA   = (ushortT*)alloc((size_t)NB * HW_ * 64 * 2);   // aliased: NB*HW*32 fp32 NHWC
    ushortT* bufB   = (ushortT*)alloc((size_t)NB * HW_ * 64 * 2);

    upsample_k<<<(BB * 4 * HW_ + 255) / 256, 256, 0, stream>>>(bfp, biflow);

    wconv_k<<<(9 * 64 * 160 + 255) / 256, 256, 0, stream>>>(W1, WbL1, 64, 64, 145, 160);
    wconv_k<<<(9 * 64 * 64 + 255) / 256, 256, 0, stream>>>(W2, WbL2, 64, 64, 64, 64);
    wconv_k<<<(9 * 64 * 64 + 255) / 256, 256, 0, stream>>>(W3, WbL3, 64, 64, 64, 64);
    wconv_k<<<(9 * 32 * 64 + 255) / 256, 256, 0, stream>>>(W4, WbL4, 32, 32, 64, 64);
    wconv_k<<<(9 * 32 * 32 + 255) / 256, 256, 0, stream>>>(W5, WbL5, 32, 32, 32, 32);
    wconv_k<<<(9 * 16 * 32 + 255) / 256, 256, 0, stream>>>(W6, WbL6, 16, 16, 32, 32);
    wconv_k<<<(9 * 16 * 32 + 255) / 256, 256, 0, stream>>>(W7, WbL7, 2, 16, 16, 32);

    for (int g = 0; g < BB; g += NB) {
        const int nb = (BB - g < NB) ? (BB - g) : NB;
        const int npix = nb * HW_;
        const float* f0g  = f0 + (size_t)g * FC * HW_;
        const float* f1g  = f1 + (size_t)g * FC * HW_;
        const float* ftfg = ftf + (size_t)g * FC * HW_;
        const float* btfg = btf + (size_t)g * FC * HW_;
        const float* bflg = biflow + (size_t)g * 4 * HW_;
        float* outg = out + (size_t)g * 4 * HW_;

        zero4_k<<<2048, 256, 0, stream>>>((uint4*)acc0, (long)nb * 33 * HW_ / 4);
        zero4_k<<<2048, 256, 0, stream>>>((uint4*)acc1, (long)nb * 33 * HW_ / 4);

        // NHWC fp32 feature copies (bufA/bufB are idle until mconv)
        tr_nhwc_k<<<(npix + 255) / 256, 256, 0, stream>>>(f0g, (float*)bufA, nb);
        tr_nhwc_k<<<(npix + 255) / 256, 256, 0, stream>>>(f1g, (float*)bufB, nb);

        // rare far-field corner events via the old atomic path
        outlier_k<<<(npix + 255) / 256, 256, 0, stream>>>(f0g, bflg, 0, acc0, nb);
        outlier_k<<<(npix + 255) / 256, 256, 0, stream>>>(f1g, bflg, 2, acc1, nb);

        // atomic-free gather splat + fused normalize
        dim3 gg(IMW / 64, IMH / 4, nb);
        gather_k<<<gg, 256, 0, stream>>>((const float*)bufA, bflg, 0, acc0);
        gather_k<<<gg, 256, 0, stream>>>((const float*)bufB, bflg, 2, acc1);

        corr_k<<<(npix + 255) / 256, 256, 0, stream>>>(acc0, acc1, concat, nb);

        dim3 cg(5, 192, nb);
        for (int pass = 0; pass < 2; ++pass) {
            const float* wp = pass ? acc1 : acc0;
            const float* tf = pass ? btfg : ftfg;
            int chB = pass ? 2 : 0;
            fill_k<<<(npix * 8 + 255) / 256, 256, 0, stream>>>(wp, tf, concat, nb);
            mconv_k<4, 5, false, false><<<cg, 256, 0, stream>>>(concat, 160, 160, WbL1, bufA, 64, nullptr, nullptr, 0);
            mconv_k<4, 2, false, false><<<cg, 256, 0, stream>>>(bufA, 64, 64, WbL2, bufB, 64, nullptr, nullptr, 0);
            mconv_k<4, 2, true,  false><<<cg, 256, 0, stream>>>(bufB, 64, 64, WbL3, bufA, 64, nullptr, nullptr, 0);
            mconv_k<2, 2, false, false><<<cg, 256, 0, stream>>>(bufA, 64, 64, WbL4, bufB, 32, nullptr, nullptr, 0);
            mconv_k<2, 1, false, false><<<cg, 256, 0, stream>>>(bufB, 32, 32, WbL5, bufA, 32, nullptr, nullptr, 0);
            mconv_k<1, 1, false, false><<<cg, 256, 0, stream>>>(bufA, 32, 32, WbL6, bufB, 16, nullptr, nullptr, 0);
            mconv_k<1, 1, true,  true ><<<cg, 256, 0, stream>>>(bufB, 16, 16, WbL7, nullptr, 0, bflg, outg, chB);
        }
    }
}

// Round 2
// 3064.313 us; speedup vs baseline: 2.0977x; 1.2888x over previous
//
#include <hip/hip_runtime.h>

// Problem constants (B=8, C=32, H=192, W=320)
#define IMH 192
#define IMW 320
#define HW_ (IMH * IMW)      // 61440
#define BB 8
#define FC 32
#define GR 8                 // gather radius: covers |disp| < 8 (~4 sigma)

typedef unsigned short ushortT;
typedef __attribute__((ext_vector_type(8))) short short8;   // 8 bf16 = 4 VGPRs
typedef __attribute__((ext_vector_type(4))) float f32x4;

union FragU { uint4 u; short8 s8; };

__device__ __forceinline__ ushortT f2bf(float x) {
    union { float f; unsigned u; } v; v.f = x;
    unsigned r = v.u + 0x7FFF + ((v.u >> 16) & 1);   // RNE
    return (ushortT)(r >> 16);
}
__device__ __forceinline__ float lk(float v) { return (v >= 0.f) ? v : 0.1f * v; }

// ---------------------------------------------------------------------------
// 1. bilinear 2x upsample (half-pixel centers, edge clamp) * 2.0  [full batch]
// ---------------------------------------------------------------------------
__global__ __launch_bounds__(256) void upsample_k(const float* __restrict__ in,
                                                  float* __restrict__ out) {
    int gid = blockIdx.x * 256 + threadIdx.x;
    const int total = BB * 4 * IMH * IMW;
    if (gid >= total) return;
    int ox = gid % IMW;
    int t  = gid / IMW;
    int oy = t % IMH;
    int bc = t / IMH;
    const int Hin = IMH / 2, Win = IMW / 2;
    float sy = oy * 0.5f - 0.25f;
    float sx = ox * 0.5f - 0.25f;
    float fy = floorf(sy), fx = floorf(sx);
    float ty_ = sy - fy, tx_ = sx - fx;
    int y0 = (int)fy, x0 = (int)fx;
    int y1 = y0 + 1, x1 = x0 + 1;
    y0 = max(0, min(Hin - 1, y0)); y1 = max(0, min(Hin - 1, y1));
    x0 = max(0, min(Win - 1, x0)); x1 = max(0, min(Win - 1, x1));
    const float* p = in + (long)bc * Hin * Win;
    float v00 = p[y0 * Win + x0], v01 = p[y0 * Win + x1];
    float v10 = p[y1 * Win + x0], v11 = p[y1 * Win + x1];
    float v = (1.f - ty_) * ((1.f - tx_) * v00 + tx_ * v01) +
              ty_ * ((1.f - tx_) * v10 + tx_ * v11);
    out[gid] = 2.f * v;
}

// ---------------------------------------------------------------------------
// 2. zero-init (16B granules)
// ---------------------------------------------------------------------------
__global__ __launch_bounds__(256) void zero4_k(uint4* __restrict__ p, long n) {
    long gid = (long)blockIdx.x * 256 + threadIdx.x;
    long stride = (long)gridDim.x * 256;
    uint4 z = make_uint4(0, 0, 0, 0);
    for (long i = gid; i < n; i += stride) p[i] = z;
}

// ---------------------------------------------------------------------------
// 3a. NCHW fp32 -> NHWC fp32 transpose (per group, into bufA/bufB alias)
// ---------------------------------------------------------------------------
__global__ __launch_bounds__(256) void tr_nhwc_k(const float* __restrict__ in,
                                                 float* __restrict__ out, int nb) {
    int gid = blockIdx.x * 256 + threadIdx.x;
    if (gid >= nb * HW_) return;
    int b = gid / HW_;
    int p = gid - b * HW_;
    const float* src = in + (long)b * FC * HW_ + p;
    float buf[FC];
#pragma unroll
    for (int c = 0; c < FC; ++c) buf[c] = src[(long)c * HW_];
    float4* dst = (float4*)(out + ((long)b * HW_ + p) * FC);
#pragma unroll
    for (int c4 = 0; c4 < FC / 4; ++c4)
        dst[c4] = make_float4(buf[c4 * 4 + 0], buf[c4 * 4 + 1],
                              buf[c4 * 4 + 2], buf[c4 * 4 + 3]);
}

// ---------------------------------------------------------------------------
// 3b. outlier splat: corner-events the gather window can't see (|d| > GR).
//     EXACT complement of gather coverage, decided per corner. Rare (~4sigma).
// ---------------------------------------------------------------------------
__global__ __launch_bounds__(256) void outlier_k(const float* __restrict__ feat,
                                                 const float* __restrict__ biflow,
                                                 int fbase,
                                                 float* __restrict__ acc, int nb) {
    int gid = blockIdx.x * 256 + threadIdx.x;
    if (gid >= nb * HW_) return;
    int b = gid / HW_;
    int p = gid - b * HW_;
    int y = p / IMW, x = p - y * IMW;
    const float* fl = biflow + ((long)b * 4 + fbase) * HW_;
    float fx = x + fl[p];
    float fy = y + fl[HW_ + p];
    float x0f = floorf(fx), y0f = floorf(fy);
    int ix0 = (int)x0f, iy0 = (int)y0f;
    if (ix0 >= x - GR && ix0 + 1 <= x + GR && iy0 >= y - GR && iy0 + 1 <= y + GR)
        return;
    float wx1 = fx - x0f, wy1 = fy - y0f;
    float wx0 = 1.f - wx1, wy0 = 1.f - wy1;
    float f[FC];
#pragma unroll
    for (int c = 0; c < FC; ++c) f[c] = feat[((long)b * FC + c) * HW_ + p];
    float* accb = acc + (long)b * 33 * HW_;
    const int ixs[4] = {ix0, ix0 + 1, ix0, ix0 + 1};
    const int iys[4] = {iy0, iy0, iy0 + 1, iy0 + 1};
    const float ww[4] = {wx0 * wy0, wx1 * wy0, wx0 * wy1, wx1 * wy1};
#pragma unroll
    for (int k = 0; k < 4; ++k) {
        int ix = ixs[k], iy = iys[k];
        float w = ww[k];
        if (ix < 0 || ix >= IMW || iy < 0 || iy >= IMH || w == 0.f) continue;
        int dx = ix - x, dy = iy - y;
        if (dx >= -GR && dx <= GR && dy >= -GR && dy <= GR) continue;
        int q = iy * IMW + ix;
#pragma unroll
        for (int c = 0; c < FC; ++c) atomicAdd(&accb[c * HW_ + q], f[c] * w);
        atomicAdd(&accb[32 * HW_ + q], w);
    }
}

// ---------------------------------------------------------------------------
// 3c. gather splat + normalize (fused). One thread per OUTPUT pixel.
//     Emits normalized warped features as NHWC bf16 (64B/px, contiguous).
// ---------------------------------------------------------------------------
__global__ __launch_bounds__(256) void gather_k(const float* __restrict__ tfeat,
                                                const float* __restrict__ biflow,
                                                int fbase,
                                                const float* __restrict__ acc,
                                                ushortT* __restrict__ wout) {
    const int b = blockIdx.z;
    const int xBase = blockIdx.x * 64;
    const int yBase = blockIdx.y * 4;
    __shared__ float2 sF[20][80];   // 12.8 KB

    const float* fl = biflow + ((long)b * 4 + fbase) * HW_;
    for (int u = threadIdx.x; u < 20 * 80; u += 256) {
        int wy = u / 80, wx = u - wy * 80;
        int gy = yBase - GR + wy, gx = xBase - GR + wx;
        float2 t = make_float2(-1e9f, -1e9f);   // sentinel: never matches
        if ((unsigned)gy < IMH && (unsigned)gx < IMW) {
            int p = gy * IMW + gx;
            t.x = gx + fl[p];        // MUST match outlier_k's "x + fl[p]" exactly
            t.y = gy + fl[HW_ + p];
        }
        sF[wy][wx] = t;
    }

    const int lx = threadIdx.x & 63, ly = threadIdx.x >> 6;
    const int ox = xBase + lx, oy = yBase + ly;
    const int q = oy * IMW + ox;
    const float* accb = acc + (long)b * 33 * HW_;

    // init from outlier contributions (mostly zero, cheap coalesced reads)
    float s[FC];
#pragma unroll
    for (int c = 0; c < FC; ++c) s[c] = accb[(long)c * HW_ + q];
    float nsum = accb[(long)32 * HW_ + q];

    __syncthreads();

    const float* tb = tfeat + (long)b * HW_ * FC;
    const int pBase = (yBase - GR + ly) * IMW + (xBase - GR + lx);

    for (int dy = 0; dy < 2 * GR + 1; ++dy) {
#pragma unroll 1
        for (int dx = 0; dx < 2 * GR + 1; ++dx) {
            float2 t = sF[ly + dy][lx + dx];
            float x0f = floorf(t.x), y0f = floorf(t.y);
            int dxm = ox - (int)x0f;
            int dym = oy - (int)y0f;
            if (((unsigned)dxm <= 1u) && ((unsigned)dym <= 1u)) {
                float wx1 = t.x - x0f, wy1 = t.y - y0f;
                float w = (dxm ? wx1 : 1.f - wx1) * (dym ? wy1 : 1.f - wy1);
                if (w != 0.f) {
                    nsum += w;
                    int pp = pBase + dy * IMW + dx;
                    const float4* fp = (const float4*)(tb + (long)pp * FC);
#pragma unroll
                    for (int c4 = 0; c4 < FC / 4; ++c4) {
                        float4 v = fp[c4];
                        s[c4 * 4 + 0] = fmaf(w, v.x, s[c4 * 4 + 0]);
                        s[c4 * 4 + 1] = fmaf(w, v.y, s[c4 * 4 + 1]);
                        s[c4 * 4 + 2] = fmaf(w, v.z, s[c4 * 4 + 2]);
                        s[c4 * 4 + 3] = fmaf(w, v.w, s[c4 * 4 + 3]);
                    }
                }
            }
        }
    }

    float inv = (nsum == 0.f) ? 1.f : (1.f / nsum);
    unsigned pk[16];
#pragma unroll
    for (int k = 0; k < 16; ++k) {
        unsigned lo = f2bf(s[2 * k] * inv);
        unsigned hi = f2bf(s[2 * k + 1] * inv);
        pk[k] = lo | (hi << 16);
    }
    uint4* dst = (uint4*)(wout + ((long)b * HW_ + q) * 32);
    dst[0] = *(uint4*)&pk[0];
    dst[1] = *(uint4*)&pk[4];
    dst[2] = *(uint4*)&pk[8];
    dst[3] = *(uint4*)&pk[12];
}

// ---------------------------------------------------------------------------
// 5. correlation volume (9x9, mean over 32 ch) + leaky -> concat bf16.
//    LDS-tiled NHWC bf16. Tile 32x8 px; window 40x16 px x 32ch in LDS
//    (72B site stride vs 64B payload -> <=2-way bank aliasing).
//    Channel layout: vol(dy,dx) -> concat ch 64 + dy*10 + dx (slot dx=9 and
//    ch154..159 zero-padded; wconv1_k permutes W1 cin to match). All output
//    stores are aligned dwords; per-pixel bytes 128..320 fully covered ->
//    no partial-line RMW.
// ---------------------------------------------------------------------------
__global__ __launch_bounds__(256) void corr_k(const ushortT* __restrict__ w0n,
                                              const ushortT* __restrict__ w1n,
                                              ushortT* __restrict__ concat) {
    const int b = blockIdx.z;
    const int xB = blockIdx.x * 32;
    const int yB = blockIdx.y * 8;
    __shared__ char sW[16 * 40 * 72];   // 46080 B

    const long pixBase = (long)b * HW_;

    for (int u = threadIdx.x; u < 16 * 40 * 8; u += 256) {
        int qq = u & 7;
        int site = u >> 3;
        int row = site / 40, col = site - row * 40;
        int gy = yB - 4 + row, gx = xB - 4 + col;
        uint2 v = make_uint2(0u, 0u);
        if ((unsigned)gy < IMH && (unsigned)gx < IMW)
            v = *(const uint2*)(w1n + (pixBase + (long)gy * IMW + gx) * 32 + qq * 4);
        *(uint2*)(sW + site * 72 + qq * 8) = v;
    }

    const int lx = threadIdx.x & 31, ly = threadIdx.x >> 5;
    const int ox = xB + lx, oy = yB + ly;

    unsigned wr[16];
    {
        const uint4* wp = (const uint4*)(w0n + (pixBase + (long)oy * IMW + ox) * 32);
        *(uint4*)&wr[0]  = wp[0];
        *(uint4*)&wr[4]  = wp[1];
        *(uint4*)&wr[8]  = wp[2];
        *(uint4*)&wr[12] = wp[3];
    }
    float w0f[32];
#pragma unroll
    for (int k = 0; k < 16; ++k) {
        union { unsigned u; float f; } lo, hi;
        lo.u = wr[k] << 16;
        hi.u = wr[k] & 0xffff0000u;
        w0f[2 * k]     = lo.f;
        w0f[2 * k + 1] = hi.f;
    }

    __syncthreads();

    const char* lbase = sW + (ly * 40 + lx) * 72;
    unsigned* ob = (unsigned*)concat + (pixBase + (long)oy * IMW + ox) * 80 + 32;

    for (int dy = 0; dy < 9; ++dy) {
        const char* rp = lbase + dy * (40 * 72);
        unsigned pd[5] = {0, 0, 0, 0, 0};
#pragma unroll
        for (int dx = 0; dx < 9; ++dx) {
            float s0 = 0.f, s1 = 0.f, s2 = 0.f, s3 = 0.f;
#pragma unroll
            for (int k = 0; k < 8; k += 2) {
                uint2 va = *(const uint2*)(rp + dx * 72 + k * 8);
                uint2 vb = *(const uint2*)(rp + dx * 72 + k * 8 + 8);
                union { unsigned u; float f; } c0, c1, c2, c3, d0, d1, d2, d3;
                c0.u = va.x << 16; c1.u = va.x & 0xffff0000u;
                c2.u = va.y << 16; c3.u = va.y & 0xffff0000u;
                d0.u = vb.x << 16; d1.u = vb.x & 0xffff0000u;
                d2.u = vb.y << 16; d3.u = vb.y & 0xffff0000u;
                s0 = fmaf(w0f[4 * k + 0], c0.f, s0);
                s1 = fmaf(w0f[4 * k + 1], c1.f, s1);
                s2 = fmaf(w0f[4 * k + 2], c2.f, s2);
                s3 = fmaf(w0f[4 * k + 3], c3.f, s3);
                s0 = fmaf(w0f[4 * k + 4], d0.f, s0);
                s1 = fmaf(w0f[4 * k + 5], d1.f, s1);
                s2 = fmaf(w0f[4 * k + 6], d2.f, s2);
                s3 = fmaf(w0f[4 * k + 7], d3.f, s3);
            }
            float s = ((s0 + s1) + (s2 + s3)) * (1.f / 32.f);
            s = lk(s);
            unsigned bf = f2bf(s);
            if (dx & 1) pd[dx >> 1] |= bf << 16;
            else        pd[dx >> 1] = bf;
        }
#pragma unroll
        for (int j = 0; j < 5; ++j) ob[dy * 5 + j] = pd[j];
    }
    ob[45] = 0u; ob[46] = 0u; ob[47] = 0u;   // ch154..159 zero (NaN-safe pad)
}

// ---------------------------------------------------------------------------
// 6. fill concat ch0..63: warped (NHWC bf16 copy) + temporal (pre-offset)
// ---------------------------------------------------------------------------
__global__ __launch_bounds__(256) void fill_k(const ushortT* __restrict__ wn,
                                              const float* __restrict__ tf,
                                              ushortT* __restrict__ concat, int nb) {
    int gid = blockIdx.x * 256 + threadIdx.x;
    if (gid >= nb * HW_ * 8) return;
    int c8 = gid & 7;
    int t = gid >> 3;
    int p = t % HW_;
    int b = t / HW_;
    int ch = c8 * 8;
    uint4 v;
    if (ch < 32) {
        v = *(const uint4*)&wn[((long)b * HW_ + p) * 32 + ch];
    } else {
        const float* src = tf + ((long)b * 32 + (ch - 32)) * HW_ + p;
        ushortT pk[8];
#pragma unroll
        for (int j = 0; j < 8; ++j) pk[j] = f2bf(src[(long)j * HW_]);
        v = *(uint4*)pk;
    }
    *(uint4*)&concat[((long)b * HW_ + p) * 160 + ch] = v;
}

// ---------------------------------------------------------------------------
// 7a. weight transform (generic): W[oc][cin][3][3] fp32 -> Wb[tap][ocp][cinp]
// ---------------------------------------------------------------------------
__global__ __launch_bounds__(256) void wconv_k(const float* __restrict__ W,
                                               ushortT* __restrict__ dst,
                                               int OC, int OCp, int CIN, int CINp) {
    int gid = blockIdx.x * 256 + threadIdx.x;
    int total = 9 * OCp * CINp;
    if (gid >= total) return;
    int cin = gid % CINp;
    int t = gid / CINp;
    int oc = t % OCp;
    int tap = t / OCp;
    float v = 0.f;
    if (oc < OC && cin < CIN) v = W[((long)oc * CIN + cin) * 9 + tap];
    dst[gid] = f2bf(v);
}

// ---------------------------------------------------------------------------
// 7b. weight transform for L1 with the corr channel permutation:
//     concat cin' = {0..63: direct, 64+dy*10+dx (dx<9): W cin 64+dy*9+dx,
//                    else zero}
// ---------------------------------------------------------------------------
__global__ __launch_bounds__(256) void wconv1_k(const float* __restrict__ W,
                                                ushortT* __restrict__ dst) {
    int gid = blockIdx.x * 256 + threadIdx.x;
    const int total = 9 * 64 * 160;
    if (gid >= total) return;
    int cin = gid % 160;
    int t = gid / 160;
    int oc = t % 64;
    int tap = t / 64;
    int src = -1;
    if (cin < 64) src = cin;
    else {
        int tt = cin - 64;            // 0..95
        int dy = tt / 10, dx = tt - dy * 10;
        if (dy < 9 && dx < 9) src = 64 + dy * 9 + dx;
    }
    float v = 0.f;
    if (src >= 0) v = W[((long)oc * 145 + src) * 9 + tap];
    dst[gid] = f2bf(v);
}

// ---------------------------------------------------------------------------
// 8. MFMA implicit-GEMM conv3x3 (SAME). Block = 256 thr = 4 waves; tile = one
//    row x 64 px. Wave w owns 16-px N-tile, loops MT M-tiles (16 oc).
// ---------------------------------------------------------------------------
template <int MT, int KC, bool LK, bool FIN>
__global__ __launch_bounds__(256) void mconv_k(
    const ushortT* __restrict__ act, int actStride, int cinReal,
    const ushortT* __restrict__ Wb,
    ushortT* __restrict__ outp, int outStride,
    const float* __restrict__ bfp, float* __restrict__ fout, int chBase) {

    const int CINp = KC * 32;
    const int OCp = MT * 16;
    const int tid = threadIdx.x;
    const int lane = tid & 63;
    const int wv = tid >> 6;
    const int l15 = lane & 15;
    const int quad = lane >> 4;
    const int x0 = blockIdx.x * 64;    // 5 tiles
    const int y = blockIdx.y;          // 192
    const int b = blockIdx.z;          // local batch

    __shared__ ushortT sAct[3 * 66 * 36];   // 14.26 KB

    f32x4 acc[MT];
#pragma unroll
    for (int i = 0; i < MT; ++i) acc[i] = (f32x4)0.f;

    const long pixBase = (long)b * HW_;

    for (int kc = 0; kc < KC; ++kc) {
        __syncthreads();
        for (int u = tid; u < 3 * 66 * 4; u += 256) {
            int c8 = u & 3;
            int site = u >> 2;
            int ky = site / 66;
            int xi = site - ky * 66;
            int gy = y + ky - 1;
            int gx = x0 + xi - 1;
            int cBeg = kc * 32 + c8 * 8;
            ushortT* dp = &sAct[site * 36 + c8 * 8];
            if ((unsigned)gy < IMH && (unsigned)gx < IMW && cBeg < cinReal) {
                const ushortT* sp = act + ((pixBase + (long)gy * IMW + gx) * actStride + cBeg);
                if (cBeg + 8 <= cinReal) {
                    const uint2* sq = (const uint2*)sp;
                    ((uint2*)dp)[0] = sq[0];
                    ((uint2*)dp)[1] = sq[1];
                } else {
#pragma unroll
                    for (int j = 0; j < 8; ++j)
                        dp[j] = (cBeg + j < cinReal) ? sp[j] : (ushortT)0;
                }
            } else {
                uint2 z = make_uint2(0, 0);
                ((uint2*)dp)[0] = z;
                ((uint2*)dp)[1] = z;
            }
        }
        __syncthreads();

#pragma unroll
        for (int tap = 0; tap < 9; ++tap) {
            const int ky = tap / 3, kx = tap % 3;
            const int xi = wv * 16 + l15 + kx;
            const uint2* bp = (const uint2*)&sAct[(ky * 66 + xi) * 36 + quad * 8];
            FragU bf;
            uint2 b0 = bp[0], b1 = bp[1];
            bf.u = make_uint4(b0.x, b0.y, b1.x, b1.y);
            const ushortT* wp = Wb + (((long)tap * OCp + l15) * CINp + kc * 32 + quad * 8);
#pragma unroll
            for (int mt = 0; mt < MT; ++mt) {
                FragU af;
                af.u = *(const uint4*)(wp + (long)mt * 16 * CINp);
                acc[mt] = __builtin_amdgcn_mfma_f32_16x16x32_bf16(af.s8, bf.s8, acc[mt], 0, 0, 0);
            }
        }
    }

    const int px = x0 + wv * 16 + l15;
    if (FIN) {
        if (quad == 0) {
#pragma unroll
            for (int r = 0; r < 2; ++r) {
                float v = lk(acc[0][r]);
                long o = ((long)(b * 4 + chBase + r) * IMH + y) * IMW + px;
                fout[o] = bfp[o] + v;
            }
        }
    } else {
        long obase = (pixBase + (long)y * IMW + px) * outStride;
#pragma unroll
        for (int mt = 0; mt < MT; ++mt) {
            int oc = mt * 16 + quad * 4;
            ushortT pk[4];
#pragma unroll
            for (int r = 0; r < 4; ++r) {
                float v = acc[mt][r];
                if (LK) v = lk(v);
                pk[r] = f2bf(v);
            }
            *(uint2*)&outp[obase + oc] = *(uint2*)pk;
        }
    }
}

// ---------------------------------------------------------------------------
// launch — ws-size-adaptive batch grouping
// ---------------------------------------------------------------------------
extern "C" void kernel_launch(void* const* d_in, const int* in_sizes, int n_in,
                              void* d_out, int out_size, void* d_ws, size_t ws_size,
                              hipStream_t stream) {
    const float* f0  = (const float*)d_in[0];
    const float* f1  = (const float*)d_in[1];
    const float* bfp = (const float*)d_in[2];
    const float* ftf = (const float*)d_in[3];
    const float* btf = (const float*)d_in[4];
    const float* W1  = (const float*)d_in[5];
    const float* W2  = (const float*)d_in[6];
    const float* W3  = (const float*)d_in[7];
    const float* W4  = (const float*)d_in[8];
    const float* W5  = (const float*)d_in[9];
    const float* W6  = (const float*)d_in[10];
    const float* W7  = (const float*)d_in[11];
    float* out = (float*)d_out;

    char* base = (char*)d_ws;
    size_t off = 0;
    auto alloc = [&](size_t bytes) { char* p = base + off; off += (bytes + 255) & ~(size_t)255; return p; };

    float* biflow = (float*)alloc((size_t)BB * 4 * HW_ * 4);
    ushortT* WbL1 = (ushortT*)alloc((size_t)9 * 64 * 160 * 2);
    ushortT* WbL2 = (ushortT*)alloc((size_t)9 * 64 * 64 * 2);
    ushortT* WbL3 = (ushortT*)alloc((size_t)9 * 64 * 64 * 2);
    ushortT* WbL4 = (ushortT*)alloc((size_t)9 * 32 * 64 * 2);
    ushortT* WbL5 = (ushortT*)alloc((size_t)9 * 32 * 32 * 2);
    ushortT* WbL6 = (ushortT*)alloc((size_t)9 * 16 * 32 * 2);
    ushortT* WbL7 = (ushortT*)alloc((size_t)9 * 16 * 32 * 2);

    // per-batch bytes/px: acc0+acc1(264) + concat(320) + bufA/B(256) + w0n/w1n(128) = 968
    const size_t PERB = (size_t)968 * HW_;
    size_t remain = (ws_size > off + 4096) ? (ws_size - off - 4096) : 0;
    int NB = (int)(remain / (PERB + 4096));
    if (NB < 1) NB = 1;
    if (NB > BB) NB = BB;

    float*   acc0   = (float*)alloc((size_t)NB * 33 * HW_ * 4);
    float*   acc1   = (float*)alloc((size_t)NB * 33 * HW_ * 4);
    ushortT* concat = (ushortT*)alloc((size_t)NB * HW_ * 160 * 2);
    ushortT* bufA   = (ushortT*)alloc((size_t)NB * HW_ * 64 * 2);   // aliased: NB*HW*32 fp32 NHWC
    ushortT* bufB   = (ushortT*)alloc((size_t)NB * HW_ * 64 * 2);
    ushortT* w0n    = (ushortT*)alloc((size_t)NB * HW_ * 32 * 2);   // warped0 NHWC bf16
    ushortT* w1n    = (ushortT*)alloc((size_t)NB * HW_ * 32 * 2);   // warped1 NHWC bf16

    upsample_k<<<(BB * 4 * HW_ + 255) / 256, 256, 0, stream>>>(bfp, biflow);

    wconv1_k<<<(9 * 64 * 160 + 255) / 256, 256, 0, stream>>>(W1, WbL1);
    wconv_k<<<(9 * 64 * 64 + 255) / 256, 256, 0, stream>>>(W2, WbL2, 64, 64, 64, 64);
    wconv_k<<<(9 * 64 * 64 + 255) / 256, 256, 0, stream>>>(W3, WbL3, 64, 64, 64, 64);
    wconv_k<<<(9 * 32 * 64 + 255) / 256, 256, 0, stream>>>(W4, WbL4, 32, 32, 64, 64);
    wconv_k<<<(9 * 32 * 32 + 255) / 256, 256, 0, stream>>>(W5, WbL5, 32, 32, 32, 32);
    wconv_k<<<(9 * 16 * 32 + 255) / 256, 256, 0, stream>>>(W6, WbL6, 16, 16, 32, 32);
    wconv_k<<<(9 * 16 * 32 + 255) / 256, 256, 0, stream>>>(W7, WbL7, 2, 16, 16, 32);

    for (int g = 0; g < BB; g += NB) {
        const int nb = (BB - g < NB) ? (BB - g) : NB;
        const int npix = nb * HW_;
        const float* f0g  = f0 + (size_t)g * FC * HW_;
        const float* f1g  = f1 + (size_t)g * FC * HW_;
        const float* ftfg = ftf + (size_t)g * FC * HW_;
        const float* btfg = btf + (size_t)g * FC * HW_;
        const float* bflg = biflow + (size_t)g * 4 * HW_;
        float* outg = out + (size_t)g * 4 * HW_;

        zero4_k<<<2048, 256, 0, stream>>>((uint4*)acc0, (long)nb * 33 * HW_ / 4);
        zero4_k<<<2048, 256, 0, stream>>>((uint4*)acc1, (long)nb * 33 * HW_ / 4);

        tr_nhwc_k<<<(npix + 255) / 256, 256, 0, stream>>>(f0g, (float*)bufA, nb);
        tr_nhwc_k<<<(npix + 255) / 256, 256, 0, stream>>>(f1g, (float*)bufB, nb);

        outlier_k<<<(npix + 255) / 256, 256, 0, stream>>>(f0g, bflg, 0, acc0, nb);
        outlier_k<<<(npix + 255) / 256, 256, 0, stream>>>(f1g, bflg, 2, acc1, nb);

        dim3 gg(IMW / 64, IMH / 4, nb);
        gather_k<<<gg, 256, 0, stream>>>((const float*)bufA, bflg, 0, acc0, w0n);
        gather_k<<<gg, 256, 0, stream>>>((const float*)bufB, bflg, 2, acc1, w1n);

        dim3 cgrid(IMW / 32, IMH / 8, nb);
        corr_k<<<cgrid, 256, 0, stream>>>(w0n, w1n, concat);

        dim3 cg(5, 192, nb);
        for (int pass = 0; pass < 2; ++pass) {
            const ushortT* wn = pass ? w1n : w0n;
            const float* tf = pass ? btfg : ftfg;
            int chB = pass ? 2 : 0;
            fill_k<<<(npix * 8 + 255) / 256, 256, 0, stream>>>(wn, tf, concat, nb);
            mconv_k<4, 5, false, false><<<cg, 256, 0, stream>>>(concat, 160, 160, WbL1, bufA, 64, nullptr, nullptr, 0);
            mconv_k<4, 2, false, false><<<cg, 256, 0, stream>>>(bufA, 64, 64, WbL2, bufB, 64, nullptr, nullptr, 0);
            mconv_k<4, 2, true,  false><<<cg, 256, 0, stream>>>(bufB, 64, 64, WbL3, bufA, 64, nullptr, nullptr, 0);
            mconv_k<2, 2, false, false><<<cg, 256, 0, stream>>>(bufA, 64, 64, WbL4, bufB, 32, nullptr, nullptr, 0);
            mconv_k<2, 1, false, false><<<cg, 256, 0, stream>>>(bufB, 32, 32, WbL5, bufA, 32, nullptr, nullptr, 0);
            mconv_k<1, 1, false, false><<<cg, 256, 0, stream>>>(bufA, 32, 32, WbL6, bufB, 16, nullptr, nullptr, 0);
            mconv_k<1, 1, true,  true ><<<cg, 256, 0, stream>>>(bufB, 16, 16, WbL7, nullptr, 0, bflg, outg, chB);
        }
    }
}

// Round 3
// 1953.898 us; speedup vs baseline: 3.2898x; 1.5683x over previous
//
#include <hip/hip_runtime.h>

// Problem constants (B=8, C=32, H=192, W=320)
#define IMH 192
#define IMW 320
#define HW_ (IMH * IMW)      // 61440
#define BB 8
#define FC 32
#define GR 8                 // gather radius: covers |disp| < 8 (~4 sigma)
#define CCH 224              // concat channels/px: [p0 feat 64][corr 96][p1 feat 64]

typedef unsigned short ushortT;
typedef __attribute__((ext_vector_type(8))) short short8;   // 8 bf16 = 4 VGPRs
typedef __attribute__((ext_vector_type(4))) float f32x4;

union FragU { uint4 u; short8 s8; };

__device__ __forceinline__ ushortT f2bf(float x) {
    union { float f; unsigned u; } v; v.f = x;
    unsigned r = v.u + 0x7FFF + ((v.u >> 16) & 1);   // RNE
    return (ushortT)(r >> 16);
}
__device__ __forceinline__ float lk(float v) { return (v >= 0.f) ? v : 0.1f * v; }

// ---------------------------------------------------------------------------
// 1. bilinear 2x upsample (half-pixel centers, edge clamp) * 2.0  [full batch]
// ---------------------------------------------------------------------------
__global__ __launch_bounds__(256) void upsample_k(const float* __restrict__ in,
                                                  float* __restrict__ out) {
    int gid = blockIdx.x * 256 + threadIdx.x;
    const int total = BB * 4 * IMH * IMW;
    if (gid >= total) return;
    int ox = gid % IMW;
    int t  = gid / IMW;
    int oy = t % IMH;
    int bc = t / IMH;
    const int Hin = IMH / 2, Win = IMW / 2;
    float sy = oy * 0.5f - 0.25f;
    float sx = ox * 0.5f - 0.25f;
    float fy = floorf(sy), fx = floorf(sx);
    float ty_ = sy - fy, tx_ = sx - fx;
    int y0 = (int)fy, x0 = (int)fx;
    int y1 = y0 + 1, x1 = x0 + 1;
    y0 = max(0, min(Hin - 1, y0)); y1 = max(0, min(Hin - 1, y1));
    x0 = max(0, min(Win - 1, x0)); x1 = max(0, min(Win - 1, x1));
    const float* p = in + (long)bc * Hin * Win;
    float v00 = p[y0 * Win + x0], v01 = p[y0 * Win + x1];
    float v10 = p[y1 * Win + x0], v11 = p[y1 * Win + x1];
    float v = (1.f - ty_) * ((1.f - tx_) * v00 + tx_ * v01) +
              ty_ * ((1.f - tx_) * v10 + tx_ * v11);
    out[gid] = 2.f * v;
}

// ---------------------------------------------------------------------------
// 2. zero-init (16B granules)
// ---------------------------------------------------------------------------
__global__ __launch_bounds__(256) void zero4_k(uint4* __restrict__ p, long n) {
    long gid = (long)blockIdx.x * 256 + threadIdx.x;
    long stride = (long)gridDim.x * 256;
    uint4 z = make_uint4(0, 0, 0, 0);
    for (long i = gid; i < n; i += stride) p[i] = z;
}

// ---------------------------------------------------------------------------
// 3a. NCHW fp32 -> NHWC fp32 transpose (per group, into bufA/bufB alias)
// ---------------------------------------------------------------------------
__global__ __launch_bounds__(256) void tr_nhwc_k(const float* __restrict__ in,
                                                 float* __restrict__ out, int nb) {
    int gid = blockIdx.x * 256 + threadIdx.x;
    if (gid >= nb * HW_) return;
    int b = gid / HW_;
    int p = gid - b * HW_;
    const float* src = in + (long)b * FC * HW_ + p;
    float buf[FC];
#pragma unroll
    for (int c = 0; c < FC; ++c) buf[c] = src[(long)c * HW_];
    float4* dst = (float4*)(out + ((long)b * HW_ + p) * FC);
#pragma unroll
    for (int c4 = 0; c4 < FC / 4; ++c4)
        dst[c4] = make_float4(buf[c4 * 4 + 0], buf[c4 * 4 + 1],
                              buf[c4 * 4 + 2], buf[c4 * 4 + 3]);
}

// ---------------------------------------------------------------------------
// 3b. outlier splat: corner-events the gather window can't see (|d| > GR).
//     EXACT complement of gather coverage, decided per corner. Rare (~4sigma).
// ---------------------------------------------------------------------------
__global__ __launch_bounds__(256) void outlier_k(const float* __restrict__ feat,
                                                 const float* __restrict__ biflow,
                                                 int fbase,
                                                 float* __restrict__ acc, int nb) {
    int gid = blockIdx.x * 256 + threadIdx.x;
    if (gid >= nb * HW_) return;
    int b = gid / HW_;
    int p = gid - b * HW_;
    int y = p / IMW, x = p - y * IMW;
    const float* fl = biflow + ((long)b * 4 + fbase) * HW_;
    float fx = x + fl[p];
    float fy = y + fl[HW_ + p];
    float x0f = floorf(fx), y0f = floorf(fy);
    int ix0 = (int)x0f, iy0 = (int)y0f;
    if (ix0 >= x - GR && ix0 + 1 <= x + GR && iy0 >= y - GR && iy0 + 1 <= y + GR)
        return;
    float wx1 = fx - x0f, wy1 = fy - y0f;
    float wx0 = 1.f - wx1, wy0 = 1.f - wy1;
    float f[FC];
#pragma unroll
    for (int c = 0; c < FC; ++c) f[c] = feat[((long)b * FC + c) * HW_ + p];
    float* accb = acc + (long)b * 33 * HW_;
    const int ixs[4] = {ix0, ix0 + 1, ix0, ix0 + 1};
    const int iys[4] = {iy0, iy0, iy0 + 1, iy0 + 1};
    const float ww[4] = {wx0 * wy0, wx1 * wy0, wx0 * wy1, wx1 * wy1};
#pragma unroll
    for (int k = 0; k < 4; ++k) {
        int ix = ixs[k], iy = iys[k];
        float w = ww[k];
        if (ix < 0 || ix >= IMW || iy < 0 || iy >= IMH || w == 0.f) continue;
        int dx = ix - x, dy = iy - y;
        if (dx >= -GR && dx <= GR && dy >= -GR && dy <= GR) continue;
        int q = iy * IMW + ix;
#pragma unroll
        for (int c = 0; c < FC; ++c) atomicAdd(&accb[c * HW_ + q], f[c] * w);
        atomicAdd(&accb[32 * HW_ + q], w);
    }
}

// ---------------------------------------------------------------------------
// 3c. gather splat + normalize (fused). One thread per OUTPUT pixel.
//     Emits normalized warped features as bf16 directly into the concat
//     section (chOff = 0 for side0, 160 for side1), stride CCH.
// ---------------------------------------------------------------------------
__global__ __launch_bounds__(256) void gather_k(const float* __restrict__ tfeat,
                                                const float* __restrict__ biflow,
                                                int fbase,
                                                const float* __restrict__ acc,
                                                ushortT* __restrict__ concat,
                                                int chOff) {
    const int b = blockIdx.z;
    const int xBase = blockIdx.x * 64;
    const int yBase = blockIdx.y * 4;
    __shared__ float2 sF[20][80];   // 12.8 KB

    const float* fl = biflow + ((long)b * 4 + fbase) * HW_;
    for (int u = threadIdx.x; u < 20 * 80; u += 256) {
        int wy = u / 80, wx = u - wy * 80;
        int gy = yBase - GR + wy, gx = xBase - GR + wx;
        float2 t = make_float2(-1e9f, -1e9f);   // sentinel: never matches
        if ((unsigned)gy < IMH && (unsigned)gx < IMW) {
            int p = gy * IMW + gx;
            t.x = gx + fl[p];        // MUST match outlier_k's "x + fl[p]" exactly
            t.y = gy + fl[HW_ + p];
        }
        sF[wy][wx] = t;
    }

    const int lx = threadIdx.x & 63, ly = threadIdx.x >> 6;
    const int ox = xBase + lx, oy = yBase + ly;
    const int q = oy * IMW + ox;
    const float* accb = acc + (long)b * 33 * HW_;

    // init from outlier contributions (mostly zero, cheap coalesced reads)
    float s[FC];
#pragma unroll
    for (int c = 0; c < FC; ++c) s[c] = accb[(long)c * HW_ + q];
    float nsum = accb[(long)32 * HW_ + q];

    __syncthreads();

    const float* tb = tfeat + (long)b * HW_ * FC;
    const int pBase = (yBase - GR + ly) * IMW + (xBase - GR + lx);

    for (int dy = 0; dy < 2 * GR + 1; ++dy) {
#pragma unroll 1
        for (int dx = 0; dx < 2 * GR + 1; ++dx) {
            float2 t = sF[ly + dy][lx + dx];
            float x0f = floorf(t.x), y0f = floorf(t.y);
            int dxm = ox - (int)x0f;
            int dym = oy - (int)y0f;
            if (((unsigned)dxm <= 1u) && ((unsigned)dym <= 1u)) {
                float wx1 = t.x - x0f, wy1 = t.y - y0f;
                float w = (dxm ? wx1 : 1.f - wx1) * (dym ? wy1 : 1.f - wy1);
                if (w != 0.f) {
                    nsum += w;
                    int pp = pBase + dy * IMW + dx;
                    const float4* fp = (const float4*)(tb + (long)pp * FC);
#pragma unroll
                    for (int c4 = 0; c4 < FC / 4; ++c4) {
                        float4 v = fp[c4];
                        s[c4 * 4 + 0] = fmaf(w, v.x, s[c4 * 4 + 0]);
                        s[c4 * 4 + 1] = fmaf(w, v.y, s[c4 * 4 + 1]);
                        s[c4 * 4 + 2] = fmaf(w, v.z, s[c4 * 4 + 2]);
                        s[c4 * 4 + 3] = fmaf(w, v.w, s[c4 * 4 + 3]);
                    }
                }
            }
        }
    }

    float inv = (nsum == 0.f) ? 1.f : (1.f / nsum);
    unsigned pk[16];
#pragma unroll
    for (int k = 0; k < 16; ++k) {
        unsigned lo = f2bf(s[2 * k] * inv);
        unsigned hi = f2bf(s[2 * k + 1] * inv);
        pk[k] = lo | (hi << 16);
    }
    uint4* dst = (uint4*)(concat + ((long)b * HW_ + q) * CCH + chOff);
    dst[0] = *(uint4*)&pk[0];
    dst[1] = *(uint4*)&pk[4];
    dst[2] = *(uint4*)&pk[8];
    dst[3] = *(uint4*)&pk[12];
}

// ---------------------------------------------------------------------------
// 4. temporal features fp32 NCHW -> bf16 into concat ch32..63 (ftf) and
//    ch192..223 (btf)
// ---------------------------------------------------------------------------
__global__ __launch_bounds__(256) void tconv_k(const float* __restrict__ ftf,
                                               const float* __restrict__ btf,
                                               ushortT* __restrict__ concat, int nb) {
    int gid = blockIdx.x * 256 + threadIdx.x;
    if (gid >= nb * HW_ * 8) return;
    int c8 = gid & 7;
    int t = gid >> 3;
    int p = t % HW_;
    int b = t / HW_;
    int ch = c8 * 8;                 // 0..63
    const float* src = (ch < 32) ? ftf + ((long)b * 32 + ch) * HW_ + p
                                 : btf + ((long)b * 32 + (ch - 32)) * HW_ + p;
    int chp = (ch < 32) ? (32 + ch) : (192 + (ch - 32));
    ushortT pk[8];
#pragma unroll
    for (int j = 0; j < 8; ++j) pk[j] = f2bf(src[(long)j * HW_]);
    *(uint4*)&concat[((long)b * HW_ + p) * CCH + chp] = *(uint4*)pk;
}

// ---------------------------------------------------------------------------
// 5. correlation volume (9x9, mean over 32 ch) + leaky -> concat ch64..159.
//    LDS-tiled from concat's p1-feat section. Tile 32x8 px; window 40x16 px.
//    Slot layout 64 + dy*10 + dx (dx=9 and ch154..159 zeroed).
// ---------------------------------------------------------------------------
__global__ __launch_bounds__(256) void corr_k(ushortT* __restrict__ concat) {
    const int b = blockIdx.z;
    const int xB = blockIdx.x * 32;
    const int yB = blockIdx.y * 8;
    __shared__ char sW[16 * 40 * 72];   // 46080 B

    const long pixBase = (long)b * HW_;

    for (int u = threadIdx.x; u < 16 * 40 * 8; u += 256) {
        int qq = u & 7;
        int site = u >> 3;
        int row = site / 40, col = site - row * 40;
        int gy = yB - 4 + row, gx = xB - 4 + col;
        uint2 v = make_uint2(0u, 0u);
        if ((unsigned)gy < IMH && (unsigned)gx < IMW)
            v = *(const uint2*)(concat + (pixBase + (long)gy * IMW + gx) * CCH + 160 + qq * 4);
        *(uint2*)(sW + site * 72 + qq * 8) = v;
    }

    const int lx = threadIdx.x & 31, ly = threadIdx.x >> 5;
    const int ox = xB + lx, oy = yB + ly;

    unsigned wr[16];
    {
        const uint4* wp = (const uint4*)(concat + (pixBase + (long)oy * IMW + ox) * CCH);
        *(uint4*)&wr[0]  = wp[0];
        *(uint4*)&wr[4]  = wp[1];
        *(uint4*)&wr[8]  = wp[2];
        *(uint4*)&wr[12] = wp[3];
    }
    float w0f[32];
#pragma unroll
    for (int k = 0; k < 16; ++k) {
        union { unsigned u; float f; } lo, hi;
        lo.u = wr[k] << 16;
        hi.u = wr[k] & 0xffff0000u;
        w0f[2 * k]     = lo.f;
        w0f[2 * k + 1] = hi.f;
    }

    __syncthreads();

    const char* lbase = sW + (ly * 40 + lx) * 72;
    unsigned* ob = (unsigned*)concat + (pixBase + (long)oy * IMW + ox) * (CCH / 2) + 32;

    for (int dy = 0; dy < 9; ++dy) {
        const char* rp = lbase + dy * (40 * 72);
        unsigned pd[5] = {0, 0, 0, 0, 0};
#pragma unroll
        for (int dx = 0; dx < 9; ++dx) {
            float s0 = 0.f, s1 = 0.f, s2 = 0.f, s3 = 0.f;
#pragma unroll
            for (int k = 0; k < 8; k += 2) {
                uint2 va = *(const uint2*)(rp + dx * 72 + k * 8);
                uint2 vb = *(const uint2*)(rp + dx * 72 + k * 8 + 8);
                union { unsigned u; float f; } c0, c1, c2, c3, d0, d1, d2, d3;
                c0.u = va.x << 16; c1.u = va.x & 0xffff0000u;
                c2.u = va.y << 16; c3.u = va.y & 0xffff0000u;
                d0.u = vb.x << 16; d1.u = vb.x & 0xffff0000u;
                d2.u = vb.y << 16; d3.u = vb.y & 0xffff0000u;
                s0 = fmaf(w0f[4 * k + 0], c0.f, s0);
                s1 = fmaf(w0f[4 * k + 1], c1.f, s1);
                s2 = fmaf(w0f[4 * k + 2], c2.f, s2);
                s3 = fmaf(w0f[4 * k + 3], c3.f, s3);
                s0 = fmaf(w0f[4 * k + 4], d0.f, s0);
                s1 = fmaf(w0f[4 * k + 5], d1.f, s1);
                s2 = fmaf(w0f[4 * k + 6], d2.f, s2);
                s3 = fmaf(w0f[4 * k + 7], d3.f, s3);
            }
            float s = ((s0 + s1) + (s2 + s3)) * (1.f / 32.f);
            s = lk(s);
            unsigned bf = f2bf(s);
            if (dx & 1) pd[dx >> 1] |= bf << 16;
            else        pd[dx >> 1] = bf;
        }
#pragma unroll
        for (int j = 0; j < 5; ++j) ob[dy * 5 + j] = pd[j];
    }
    ob[45] = 0u; ob[46] = 0u; ob[47] = 0u;   // ch154..159 zero (NaN-safe pad)
}

// ---------------------------------------------------------------------------
// 7a. weight transform (generic): W[oc][cin][3][3] fp32 -> Wb[tap][ocp][cinp]
// ---------------------------------------------------------------------------
__global__ __launch_bounds__(256) void wconv_k(const float* __restrict__ W,
                                               ushortT* __restrict__ dst,
                                               int OC, int OCp, int CIN, int CINp) {
    int gid = blockIdx.x * 256 + threadIdx.x;
    int total = 9 * OCp * CINp;
    if (gid >= total) return;
    int cin = gid % CINp;
    int t = gid / CINp;
    int oc = t % OCp;
    int tap = t / OCp;
    float v = 0.f;
    if (oc < OC && cin < CIN) v = W[((long)oc * CIN + cin) * 9 + tap];
    dst[gid] = f2bf(v);
}

// ---------------------------------------------------------------------------
// 7b. L1 weight transform with concat channel permutation.
//     mode 0 (pass0, act = concat+0):  cin' 0..63 feat, 64..159 corr slots
//     mode 1 (pass1, act = concat+64): cin' 0..95 corr slots, 96..159 feat
//     corr slot s = dy*10+dx -> W cin 64+dy*9+dx (dx<9, dy<9), else zero
// ---------------------------------------------------------------------------
__global__ __launch_bounds__(256) void wconv1_k(const float* __restrict__ W,
                                                ushortT* __restrict__ dst, int mode) {
    int gid = blockIdx.x * 256 + threadIdx.x;
    const int total = 9 * 64 * 160;
    if (gid >= total) return;
    int cin = gid % 160;
    int t = gid / 160;
    int oc = t % 64;
    int tap = t / 64;
    int src = -1;
    if (mode == 0) {
        if (cin < 64) src = cin;
        else {
            int tt = cin - 64;            // 0..95
            int dy = tt / 10, dx = tt - dy * 10;
            if (dy < 9 && dx < 9) src = 64 + dy * 9 + dx;
        }
    } else {
        if (cin < 96) {
            int dy = cin / 10, dx = cin - dy * 10;
            if (dy < 9 && dx < 9) src = 64 + dy * 9 + dx;
        } else {
            src = cin - 96;
        }
    }
    float v = 0.f;
    if (src >= 0) v = W[((long)oc * 145 + src) * 9 + tap];
    dst[gid] = f2bf(v);
}

// ---------------------------------------------------------------------------
// 8. MFMA implicit-GEMM conv3x3 (SAME). Block = 256 thr = 4 waves.
//    Tile = 4 rows x 64 px; wave wv owns row y0+wv (4 N-tiles of 16 px),
//    loops MT M-tiles (16 oc each). Stages 6 rows x 66 px x 32ch per kc
//    (halo 1.5x). Per tap: MT A-loads (global, L2-hot) + 4 B-reads (LDS)
//    feed MT*4 MFMAs. All pads are zero-weighted, so no cin masking.
// ---------------------------------------------------------------------------
template <int MT, int KC, bool LK, bool FIN>
__global__ __launch_bounds__(256) void mconv_k(
    const ushortT* __restrict__ act, int actStride,
    const ushortT* __restrict__ Wb,
    ushortT* __restrict__ outp, int outStride,
    const float* __restrict__ bfp, float* __restrict__ fout, int chBase) {

    const int CINp = KC * 32;
    const int OCp = MT * 16;
    const int tid = threadIdx.x;
    const int lane = tid & 63;
    const int wv = tid >> 6;
    const int l15 = lane & 15;
    const int quad = lane >> 4;
    const int x0 = blockIdx.x * 64;    // 5 tiles
    const int y0 = blockIdx.y * 4;     // 48 tiles
    const int b = blockIdx.z;          // local batch

    __shared__ ushortT sAct[6 * 66 * 36];   // 28.5 KB

    f32x4 acc[MT][4];
#pragma unroll
    for (int i = 0; i < MT; ++i)
#pragma unroll
        for (int j = 0; j < 4; ++j) acc[i][j] = (f32x4)0.f;

    const long pixBase = (long)b * HW_;

    for (int kc = 0; kc < KC; ++kc) {
        __syncthreads();
        // stage 6 rows x 66 px x 32 ch (4 units of 8ch per site)
        for (int u = tid; u < 6 * 66 * 4; u += 256) {
            int c8 = u & 3;
            int site = u >> 2;
            int ky = site / 66;               // 0..5
            int xi = site - ky * 66;
            int gy = y0 + ky - 1;
            int gx = x0 + xi - 1;
            int cBeg = kc * 32 + c8 * 8;
            ushortT* dp = &sAct[site * 36 + c8 * 8];
            uint2 v0 = make_uint2(0, 0), v1 = v0;
            if ((unsigned)gy < IMH && (unsigned)gx < IMW) {
                const uint2* sq = (const uint2*)(act + ((pixBase + (long)gy * IMW + gx) * actStride + cBeg));
                v0 = sq[0]; v1 = sq[1];
            }
            ((uint2*)dp)[0] = v0;
            ((uint2*)dp)[1] = v1;
        }
        __syncthreads();

#pragma unroll
        for (int tap = 0; tap < 9; ++tap) {
            const int ky = tap / 3, kx = tap % 3;
            const int rowb = (wv + ky) * 66;
            FragU bf[4];
#pragma unroll
            for (int nt = 0; nt < 4; ++nt) {
                const uint2* bp = (const uint2*)&sAct[(rowb + nt * 16 + l15 + kx) * 36 + quad * 8];
                uint2 b0 = bp[0], b1 = bp[1];
                bf[nt].u = make_uint4(b0.x, b0.y, b1.x, b1.y);
            }
            const ushortT* wp = Wb + (((long)tap * OCp + l15) * CINp + kc * 32 + quad * 8);
#pragma unroll
            for (int mt = 0; mt < MT; ++mt) {
                FragU af;
                af.u = *(const uint4*)(wp + (long)mt * 16 * CINp);
#pragma unroll
                for (int nt = 0; nt < 4; ++nt)
                    acc[mt][nt] = __builtin_amdgcn_mfma_f32_16x16x32_bf16(af.s8, bf[nt].s8, acc[mt][nt], 0, 0, 0);
            }
        }
    }

    const int yo = y0 + wv;
    if (FIN) {
        if (quad == 0) {
#pragma unroll
            for (int nt = 0; nt < 4; ++nt) {
                int px = x0 + nt * 16 + l15;
#pragma unroll
                for (int r = 0; r < 2; ++r) {
                    float v = lk(acc[0][nt][r]);
                    long o = ((long)(b * 4 + chBase + r) * IMH + yo) * IMW + px;
                    fout[o] = bfp[o] + v;
                }
            }
        }
    } else {
        const long rowBase = (pixBase + (long)yo * IMW) * outStride;
#pragma unroll
        for (int nt = 0; nt < 4; ++nt) {
            long obase = rowBase + (long)(x0 + nt * 16 + l15) * outStride;
#pragma unroll
            for (int mt = 0; mt < MT; ++mt) {
                int oc = mt * 16 + quad * 4;
                ushortT pk[4];
#pragma unroll
                for (int r = 0; r < 4; ++r) {
                    float v = acc[mt][nt][r];
                    if (LK) v = lk(v);
                    pk[r] = f2bf(v);
                }
                *(uint2*)&outp[obase + oc] = *(uint2*)pk;
            }
        }
    }
}

// ---------------------------------------------------------------------------
// launch — ws-size-adaptive batch grouping
// ---------------------------------------------------------------------------
extern "C" void kernel_launch(void* const* d_in, const int* in_sizes, int n_in,
                              void* d_out, int out_size, void* d_ws, size_t ws_size,
                              hipStream_t stream) {
    const float* f0  = (const float*)d_in[0];
    const float* f1  = (const float*)d_in[1];
    const float* bfp = (const float*)d_in[2];
    const float* ftf = (const float*)d_in[3];
    const float* btf = (const float*)d_in[4];
    const float* W1  = (const float*)d_in[5];
    const float* W2  = (const float*)d_in[6];
    const float* W3  = (const float*)d_in[7];
    const float* W4  = (const float*)d_in[8];
    const float* W5  = (const float*)d_in[9];
    const float* W6  = (const float*)d_in[10];
    const float* W7  = (const float*)d_in[11];
    float* out = (float*)d_out;

    char* base = (char*)d_ws;
    size_t off = 0;
    auto alloc = [&](size_t bytes) { char* p = base + off; off += (bytes + 255) & ~(size_t)255; return p; };

    float* biflow = (float*)alloc((size_t)BB * 4 * HW_ * 4);
    ushortT* WbL1a = (ushortT*)alloc((size_t)9 * 64 * 160 * 2);
    ushortT* WbL1b = (ushortT*)alloc((size_t)9 * 64 * 160 * 2);
    ushortT* WbL2 = (ushortT*)alloc((size_t)9 * 64 * 64 * 2);
    ushortT* WbL3 = (ushortT*)alloc((size_t)9 * 64 * 64 * 2);
    ushortT* WbL4 = (ushortT*)alloc((size_t)9 * 32 * 64 * 2);
    ushortT* WbL5 = (ushortT*)alloc((size_t)9 * 32 * 32 * 2);
    ushortT* WbL6 = (ushortT*)alloc((size_t)9 * 16 * 32 * 2);
    ushortT* WbL7 = (ushortT*)alloc((size_t)9 * 16 * 32 * 2);

    // per-batch bytes/px: acc0+acc1(264) + concat(448) + bufA(128) + bufB(128) = 968
    const size_t PERB = (size_t)968 * HW_;
    size_t remain = (ws_size > off + 4096) ? (ws_size - off - 4096) : 0;
    int NB = (int)(remain / (PERB + 4096));
    if (NB < 1) NB = 1;
    if (NB > BB) NB = BB;

    float*   acc0   = (float*)alloc((size_t)NB * 33 * HW_ * 4);
    float*   acc1   = (float*)alloc((size_t)NB * 33 * HW_ * 4);
    ushortT* concat = (ushortT*)alloc((size_t)NB * HW_ * CCH * 2);
    ushortT* bufA   = (ushortT*)alloc((size_t)NB * HW_ * 64 * 2);   // aliased: NB*HW*32 fp32 NHWC
    ushortT* bufB   = (ushortT*)alloc((size_t)NB * HW_ * 64 * 2);

    upsample_k<<<(BB * 4 * HW_ + 255) / 256, 256, 0, stream>>>(bfp, biflow);

    wconv1_k<<<(9 * 64 * 160 + 255) / 256, 256, 0, stream>>>(W1, WbL1a, 0);
    wconv1_k<<<(9 * 64 * 160 + 255) / 256, 256, 0, stream>>>(W1, WbL1b, 1);
    wconv_k<<<(9 * 64 * 64 + 255) / 256, 256, 0, stream>>>(W2, WbL2, 64, 64, 64, 64);
    wconv_k<<<(9 * 64 * 64 + 255) / 256, 256, 0, stream>>>(W3, WbL3, 64, 64, 64, 64);
    wconv_k<<<(9 * 32 * 64 + 255) / 256, 256, 0, stream>>>(W4, WbL4, 32, 32, 64, 64);
    wconv_k<<<(9 * 32 * 32 + 255) / 256, 256, 0, stream>>>(W5, WbL5, 32, 32, 32, 32);
    wconv_k<<<(9 * 16 * 32 + 255) / 256, 256, 0, stream>>>(W6, WbL6, 16, 16, 32, 32);
    wconv_k<<<(9 * 16 * 32 + 255) / 256, 256, 0, stream>>>(W7, WbL7, 2, 16, 16, 32);

    for (int g = 0; g < BB; g += NB) {
        const int nb = (BB - g < NB) ? (BB - g) : NB;
        const int npix = nb * HW_;
        const float* f0g  = f0 + (size_t)g * FC * HW_;
        const float* f1g  = f1 + (size_t)g * FC * HW_;
        const float* ftfg = ftf + (size_t)g * FC * HW_;
        const float* btfg = btf + (size_t)g * FC * HW_;
        const float* bflg = biflow + (size_t)g * 4 * HW_;
        float* outg = out + (size_t)g * 4 * HW_;

        // zero both acc regions (contiguous NB-sized blocks) in one dispatch
        zero4_k<<<2048, 256, 0, stream>>>((uint4*)acc0, (long)NB * 66 * HW_ / 4);

        tr_nhwc_k<<<(npix + 255) / 256, 256, 0, stream>>>(f0g, (float*)bufA, nb);
        tr_nhwc_k<<<(npix + 255) / 256, 256, 0, stream>>>(f1g, (float*)bufB, nb);

        outlier_k<<<(npix + 255) / 256, 256, 0, stream>>>(f0g, bflg, 0, acc0, nb);
        outlier_k<<<(npix + 255) / 256, 256, 0, stream>>>(f1g, bflg, 2, acc1, nb);

        dim3 gg(IMW / 64, IMH / 4, nb);
        gather_k<<<gg, 256, 0, stream>>>((const float*)bufA, bflg, 0, acc0, concat, 0);
        gather_k<<<gg, 256, 0, stream>>>((const float*)bufB, bflg, 2, acc1, concat, 160);

        tconv_k<<<(npix * 8 + 255) / 256, 256, 0, stream>>>(ftfg, btfg, concat, nb);

        dim3 cgrid(IMW / 32, IMH / 8, nb);
        corr_k<<<cgrid, 256, 0, stream>>>(concat);

        dim3 cg(5, 48, nb);
        for (int pass = 0; pass < 2; ++pass) {
            const ushortT* actL1 = concat + (pass ? 64 : 0);
            const ushortT* WbL1 = pass ? WbL1b : WbL1a;
            int chB = pass ? 2 : 0;
            mconv_k<4, 5, false, false><<<cg, 256, 0, stream>>>(actL1, CCH, WbL1, bufA, 64, nullptr, nullptr, 0);
            mconv_k<4, 2, false, false><<<cg, 256, 0, stream>>>(bufA, 64, WbL2, bufB, 64, nullptr, nullptr, 0);
            mconv_k<4, 2, true,  false><<<cg, 256, 0, stream>>>(bufB, 64, WbL3, bufA, 64, nullptr, nullptr, 0);
            mconv_k<2, 2, false, false><<<cg, 256, 0, stream>>>(bufA, 64, WbL4, bufB, 32, nullptr, nullptr, 0);
            mconv_k<2, 1, false, false><<<cg, 256, 0, stream>>>(bufB, 32, WbL5, bufA, 32, nullptr, nullptr, 0);
            mconv_k<1, 1, false, false><<<cg, 256, 0, stream>>>(bufA, 32, WbL6, bufB, 16, nullptr, nullptr, 0);
            mconv_k<1, 1, true,  true ><<<cg, 256, 0, stream>>>(bufB, 16, WbL7, nullptr, 0, bflg, outg, chB);
        }
    }
}